// Round 3
// baseline (377.948 us; speedup 1.0000x reference)
//
#include <hip/hip_runtime.h>
#include <stdint.h>

// ---------------------------------------------------------------------------
// H=512, N=8, B=4, T=1024.  All GEMMs as bf16 MFMA (m97 structure):
//   A [M][K] bf16 row-major, Bt [N][K] bf16 row-major (B transposed),
//   128x128 tile, BK=32, 4 waves (2x2), 4x4 fragments of 16x16x32 MFMA,
//   global_load_lds width-16 staging, 2-barrier K-loop.
// Narrow-N GEMMs (N=512: Wo, Wf2) use split-K over blockIdx.z with f32
//   atomicAdd epilogue to fill the machine (128 blocks -> 1024 blocks).
// Attention: softmax row-sums + diagonal computed in the logits GEMM epilogue.
// ---------------------------------------------------------------------------

#define LN_EPS 1e-5f

typedef __attribute__((ext_vector_type(8))) short short8;
typedef __attribute__((ext_vector_type(4))) float f32x4;

__device__ __forceinline__ unsigned short f2bf(float f) {
    unsigned int u = __float_as_uint(f);
    u = (u + 0x7fffu + ((u >> 16) & 1u)) >> 16;
    return (unsigned short)u;
}
__device__ __forceinline__ float bf2f(unsigned short h) {
    return __uint_as_float(((unsigned int)h) << 16);
}

__device__ __forceinline__ void llds16(const void* g, void* l) {
    __builtin_amdgcn_global_load_lds(
        (const __attribute__((address_space(1))) void*)g,
        (__attribute__((address_space(3))) void*)l, 16, 0, 0);
}

#define OUT_F32 0
#define OUT_BF16 1
#define OUT_ATTN 2
#define OUT_F32A 3   // f32 atomicAdd (split-K)

// ---------------------------------------------------------------------------
// bf16 MFMA GEMM: C = act(A @ Bt^T + bias).  M,N multiples of 128; K of 32.
// SPLITK: blockIdx.z = K-chunk index (Kc = K/gridDim.z); MODE must be OUT_F32A,
//         C pre-zeroed, bias added by chunk 0 only, no RELU.
// Else:   blockIdx.z = batch index (aBatch/bBatch element strides).
// ---------------------------------------------------------------------------
template <int MODE, bool BIAS, bool RELU, bool SPLITK>
__global__ __launch_bounds__(256) void gemm_bt(
    const unsigned short* __restrict__ A,   // [M][K] bf16
    const unsigned short* __restrict__ Bt,  // [N][K] bf16
    const float* __restrict__ bias,         // [N] f32
    void* __restrict__ Cv,                  // [M][N] f32 or bf16 (unused ATTN)
    float* __restrict__ dsum,               // ATTN: [32768] f32 (pre-zeroed)
    float* __restrict__ ddiag,              // ATTN: [32768] f32
    int M, int N, int K,
    long aBatch, long bBatch, float scale) {
    __shared__ unsigned short As[128 * 32];  // [row][k] 64B rows
    __shared__ unsigned short Bs[128 * 32];

    const int tid = threadIdx.x;
    const int wid = tid >> 6;
    const int lane = tid & 63;
    const int lr = lane & 15;   // fragment row/col within 16
    const int kg = lane >> 4;   // k-group 0..3
    const int wr = wid >> 1;
    const int wc = wid & 1;
    const int row0 = blockIdx.y * 128;
    const int col0 = blockIdx.x * 128;

    const unsigned short* Ab = A;
    const unsigned short* Bb = Bt;
    int kbeg = 0, kend = K;
    if (SPLITK) {
        const int Kc = K / gridDim.z;
        kbeg = blockIdx.z * Kc;
        kend = kbeg + Kc;
    } else {
        Ab += (long)blockIdx.z * aBatch;
        Bb += (long)blockIdx.z * bBatch;
    }

    // staging: per wave 2 calls of 1KB each for A and B
    const int rS = wid * 32 + (lane >> 2);  // row in 128-tile (call 0)
    const int k8 = (lane & 3) * 8;          // bf16 offset within 32-k row
    unsigned short* ldsA0 = &As[(wid * 2 + 0) * 512];
    unsigned short* ldsA1 = &As[(wid * 2 + 1) * 512];
    unsigned short* ldsB0 = &Bs[(wid * 2 + 0) * 512];
    unsigned short* ldsB1 = &Bs[(wid * 2 + 1) * 512];
    const unsigned short* gA0 = Ab + (long)(row0 + rS) * K + k8;
    const unsigned short* gA1 = gA0 + (long)16 * K;
    const unsigned short* gB0 = Bb + (long)(col0 + rS) * K + k8;
    const unsigned short* gB1 = gB0 + (long)16 * K;

    f32x4 acc[4][4];
#pragma unroll
    for (int m = 0; m < 4; ++m)
#pragma unroll
        for (int n = 0; n < 4; ++n)
#pragma unroll
            for (int j = 0; j < 4; ++j) acc[m][n][j] = 0.f;

    for (int kk = kbeg; kk < kend; kk += 32) {
        __syncthreads();  // previous ds_reads done before overwrite
        llds16(gA0 + kk, ldsA0);
        llds16(gA1 + kk, ldsA1);
        llds16(gB0 + kk, ldsB0);
        llds16(gB1 + kk, ldsB1);
        __syncthreads();  // drains vmcnt -> LDS tiles ready
        short8 a[4], b[4];
#pragma unroll
        for (int m = 0; m < 4; ++m)
            a[m] = *(const short8*)&As[(wr * 64 + m * 16 + lr) * 32 + kg * 8];
#pragma unroll
        for (int n = 0; n < 4; ++n)
            b[n] = *(const short8*)&Bs[(wc * 64 + n * 16 + lr) * 32 + kg * 8];
#pragma unroll
        for (int m = 0; m < 4; ++m)
#pragma unroll
            for (int n = 0; n < 4; ++n)
                acc[m][n] = __builtin_amdgcn_mfma_f32_16x16x32_bf16(
                    a[m], b[n], acc[m][n], 0, 0, 0);
    }

    if (MODE == OUT_ATTN) {
        // rows of this wave: row0 + wr*64 + m*16 + kg*4 + j  (per head bz)
        const int hrow0 = blockIdx.z * 1024 + row0 + wr * 64;
        const bool diagblk = (blockIdx.x == blockIdx.y) && (wr == wc);
#pragma unroll
        for (int m = 0; m < 4; ++m) {
            float es[4] = {0.f, 0.f, 0.f, 0.f};
#pragma unroll
            for (int n = 0; n < 4; ++n) {
#pragma unroll
                for (int j = 0; j < 4; ++j) {
                    float e = __expf(acc[m][n][j] * scale);
                    es[j] += e;
                    if (diagblk && n == m && lr == kg * 4 + j)
                        ddiag[hrow0 + m * 16 + kg * 4 + j] = e;
                }
            }
#pragma unroll
            for (int j = 0; j < 4; ++j) {
                float s = es[j];
                s += __shfl_xor(s, 1, 64);
                s += __shfl_xor(s, 2, 64);
                s += __shfl_xor(s, 4, 64);
                s += __shfl_xor(s, 8, 64);
                if (lr == 0) atomicAdd(&dsum[hrow0 + m * 16 + kg * 4 + j], s);
            }
        }
        return;
    }

    const bool addBias = BIAS && (!SPLITK || blockIdx.z == 0);
#pragma unroll
    for (int m = 0; m < 4; ++m) {
        const int grow = row0 + wr * 64 + m * 16 + kg * 4;
#pragma unroll
        for (int n = 0; n < 4; ++n) {
            const int gcol = col0 + wc * 64 + n * 16 + lr;
            const float bv = addBias ? bias[gcol] : 0.f;
#pragma unroll
            for (int j = 0; j < 4; ++j) {
                float v = acc[m][n][j] + bv;
                if (RELU) v = fmaxf(v, 0.f);
                if (MODE == OUT_F32)
                    ((float*)Cv)[(long)(grow + j) * N + gcol] = v;
                else if (MODE == OUT_F32A)
                    atomicAdd(&((float*)Cv)[(long)(grow + j) * N + gcol], v);
                else
                    ((unsigned short*)Cv)[(long)(grow + j) * N + gcol] = f2bf(v);
            }
        }
    }
}

// ---------------------------------------------------------------------------
// f32 [R][C] -> bf16 [C][R] transpose+convert (weights, once per launch)
// ---------------------------------------------------------------------------
__global__ __launch_bounds__(256) void transpose_bf16(
    const float* __restrict__ src, unsigned short* __restrict__ dst,
    int R, int C) {
    __shared__ float tile[32][33];
    const int tx = threadIdx.x & 31;
    const int ty = threadIdx.x >> 5;  // 0..7
    const int r0 = blockIdx.y * 32;
    const int c0 = blockIdx.x * 32;
#pragma unroll
    for (int k = 0; k < 4; ++k)
        tile[ty + k * 8][tx] = src[(long)(r0 + ty + k * 8) * C + c0 + tx];
    __syncthreads();
#pragma unroll
    for (int k = 0; k < 4; ++k)
        dst[(long)(c0 + ty + k * 8) * R + r0 + tx] = f2bf(tile[tx][ty + k * 8]);
}

// f32 -> bf16 flat convert, 8 elems/thread
__global__ __launch_bounds__(256) void convert_bf16(
    const float* __restrict__ src, unsigned short* __restrict__ dst, int n8) {
    const int idx = blockIdx.x * 256 + threadIdx.x;
    if (idx >= n8) return;
    float4 a = ((const float4*)src)[idx * 2];
    float4 b = ((const float4*)src)[idx * 2 + 1];
    uint4 o;
    o.x = (unsigned int)f2bf(a.x) | ((unsigned int)f2bf(a.y) << 16);
    o.y = (unsigned int)f2bf(a.z) | ((unsigned int)f2bf(a.w) << 16);
    o.z = (unsigned int)f2bf(b.x) | ((unsigned int)f2bf(b.y) << 16);
    o.w = (unsigned int)f2bf(b.z) | ((unsigned int)f2bf(b.w) << 16);
    ((uint4*)dst)[idx] = o;
}

// ---------------------------------------------------------------------------
// In-place diagonal-softmax scale of bf16 V rows (viewed [32768][512]):
//   V[r,:] *= ddiag[r]/dsum[r]
// ---------------------------------------------------------------------------
__global__ __launch_bounds__(256) void scale_v_kernel(
    unsigned short* __restrict__ V, const float* __restrict__ dsum,
    const float* __restrict__ ddiag, int nChunks) {
    const int idx = blockIdx.x * 256 + threadIdx.x;
    if (idx >= nChunks) return;
    const int row = idx >> 6;  // 64 chunks of 8 bf16 per 512-col row
    const float s = ddiag[row] / dsum[row];
    uint4 v = ((const uint4*)V)[idx];
    unsigned int w[4] = {v.x, v.y, v.z, v.w};
#pragma unroll
    for (int i = 0; i < 4; ++i) {
        const float lo = bf2f((unsigned short)(w[i] & 0xffffu)) * s;
        const float hi = bf2f((unsigned short)(w[i] >> 16)) * s;
        w[i] = (unsigned int)f2bf(lo) | ((unsigned int)f2bf(hi) << 16);
    }
    uint4 o;
    o.x = w[0]; o.y = w[1]; o.z = w[2]; o.w = w[3];
    ((uint4*)V)[idx] = o;
}

// ---------------------------------------------------------------------------
// Fused residual-add + LayerNorm (rows of 512); optional bf16 side-output.
// ---------------------------------------------------------------------------
template <bool WB>
__global__ __launch_bounds__(256) void add_ln_kernel(
    const float* __restrict__ A, const float* __restrict__ Bv,
    const float* __restrict__ g, const float* __restrict__ be,
    float* __restrict__ out, unsigned short* __restrict__ outb) {
    __shared__ float sred[8];
    __shared__ float sred2[8];
    const int row = blockIdx.x;
    const int tid = threadIdx.x;
    const float* a = A + (long)row * 512;
    const float* b = Bv + (long)row * 512;

    const float v0 = a[tid] + b[tid];
    const float v1 = a[tid + 256] + b[tid + 256];
    float sum = v0 + v1;
    float sq = v0 * v0 + v1 * v1;
#pragma unroll
    for (int off = 32; off > 0; off >>= 1) {
        sum += __shfl_down(sum, off, 64);
        sq += __shfl_down(sq, off, 64);
    }
    const int wave = tid >> 6;
    if ((tid & 63) == 0) { sred[wave] = sum; sred2[wave] = sq; }
    __syncthreads();
    if (tid == 0) {
        float s = 0.f, q = 0.f;
#pragma unroll
        for (int w = 0; w < 4; ++w) { s += sred[w]; q += sred2[w]; }
        const float mu = s * (1.f / 512.f);
        const float var = q * (1.f / 512.f) - mu * mu;
        sred[4] = mu;
        sred2[4] = rsqrtf(var + LN_EPS);
    }
    __syncthreads();
    const float mu = sred[4];
    const float rs = sred2[4];
    const float o0 = (v0 - mu) * rs * g[tid] + be[tid];
    const float o1 = (v1 - mu) * rs * g[tid + 256] + be[tid + 256];
    out[(long)row * 512 + tid] = o0;
    out[(long)row * 512 + tid + 256] = o1;
    if (WB) {
        outb[(long)row * 512 + tid] = f2bf(o0);
        outb[(long)row * 512 + tid + 256] = f2bf(o1);
    }
}

// ---------------------------------------------------------------------------
// Launcher
// ---------------------------------------------------------------------------
extern "C" void kernel_launch(void* const* d_in, const int* in_sizes, int n_in,
                              void* d_out, int out_size, void* d_ws, size_t ws_size,
                              hipStream_t stream) {
    const float* x     = (const float*)d_in[0];
    const float* Wq    = (const float*)d_in[1];
    const float* Wk    = (const float*)d_in[2];
    const float* Wv    = (const float*)d_in[3];
    const float* Wo    = (const float*)d_in[4];
    const float* g1    = (const float*)d_in[5];
    const float* beta1 = (const float*)d_in[6];
    const float* Wf1   = (const float*)d_in[7];
    const float* bf1   = (const float*)d_in[8];
    const float* Wf2   = (const float*)d_in[9];
    const float* bf2   = (const float*)d_in[10];
    const float* g2    = (const float*)d_in[11];
    const float* beta2 = (const float*)d_in[12];
    float* out = (float*)d_out;

    char* p = (char*)d_ws;
    unsigned short* xb   = (unsigned short*)p; p += (long)4096 * 512 * 2;
    unsigned short* WqT  = (unsigned short*)p; p += (long)4096 * 512 * 2;
    unsigned short* WkT  = (unsigned short*)p; p += (long)4096 * 512 * 2;
    unsigned short* WvT  = (unsigned short*)p; p += (long)4096 * 512 * 2;
    unsigned short* WoT  = (unsigned short*)p; p += (long)512 * 4096 * 2;
    unsigned short* Wf1T = (unsigned short*)p; p += (long)2048 * 512 * 2;
    unsigned short* Wf2T = (unsigned short*)p; p += (long)512 * 2048 * 2;
    unsigned short* Qb   = (unsigned short*)p; p += (long)4096 * 4096 * 2;
    unsigned short* Kb   = (unsigned short*)p; p += (long)4096 * 4096 * 2;
    unsigned short* Vb   = (unsigned short*)p; p += (long)4096 * 4096 * 2;
    float* dsum  = (float*)p; p += (long)32768 * 4;
    float* ddiag = (float*)p; p += (long)32768 * 4;
    float* attn  = (float*)p; p += (long)4096 * 512 * 4;
    float* y1    = (float*)p; p += (long)4096 * 512 * 4;
    unsigned short* y1b = (unsigned short*)p; p += (long)4096 * 512 * 2;
    unsigned short* f1b = (unsigned short*)p; p += (long)4096 * 2048 * 2;
    float* ff    = (float*)p; p += (long)4096 * 512 * 4;

    const dim3 blk(256);
    const float invs = 0.04419417382415922f;  // 1/sqrt(512)

    // 0. converts / weight transposes (bf16, B^T form)
    convert_bf16<<<dim3(1024), blk, 0, stream>>>(x, xb, 4096 * 512 / 8);
    transpose_bf16<<<dim3(4096 / 32, 512 / 32), blk, 0, stream>>>(Wq, WqT, 512, 4096);
    transpose_bf16<<<dim3(4096 / 32, 512 / 32), blk, 0, stream>>>(Wk, WkT, 512, 4096);
    transpose_bf16<<<dim3(4096 / 32, 512 / 32), blk, 0, stream>>>(Wv, WvT, 512, 4096);
    transpose_bf16<<<dim3(512 / 32, 4096 / 32), blk, 0, stream>>>(Wo, WoT, 4096, 512);
    transpose_bf16<<<dim3(2048 / 32, 512 / 32), blk, 0, stream>>>(Wf1, Wf1T, 512, 2048);
    transpose_bf16<<<dim3(512 / 32, 2048 / 32), blk, 0, stream>>>(Wf2, Wf2T, 2048, 512);

    // zero atomic-accumulated buffers + dsum
    hipMemsetAsync(dsum, 0, 32768 * sizeof(float), stream);
    hipMemsetAsync(attn, 0, (long)4096 * 512 * sizeof(float), stream);
    hipMemsetAsync(ff, 0, (long)4096 * 512 * sizeof(float), stream);

    // 1. QKV projections (bf16 out)
    gemm_bt<OUT_BF16, false, false, false><<<dim3(32, 32, 1), blk, 0, stream>>>(
        xb, WqT, nullptr, Qb, nullptr, nullptr, 4096, 4096, 512, 0, 0, 1.f);
    gemm_bt<OUT_BF16, false, false, false><<<dim3(32, 32, 1), blk, 0, stream>>>(
        xb, WkT, nullptr, Kb, nullptr, nullptr, 4096, 4096, 512, 0, 0, 1.f);
    gemm_bt<OUT_BF16, false, false, false><<<dim3(32, 32, 1), blk, 0, stream>>>(
        xb, WvT, nullptr, Vb, nullptr, nullptr, 4096, 4096, 512, 0, 0, 1.f);

    // 2. logits + softmax row-sums/diag (Q,K viewed [32 heads][1024][512])
    gemm_bt<OUT_ATTN, false, false, false><<<dim3(8, 8, 32), blk, 0, stream>>>(
        Qb, Kb, nullptr, nullptr, dsum, ddiag, 1024, 1024, 512,
        (long)1024 * 512, (long)1024 * 512, invs);

    // 3. hh = diag(attn) * V, in place on Vb
    scale_v_kernel<<<dim3(32768 * 512 / 8 / 256), blk, 0, stream>>>(
        Vb, dsum, ddiag, 32768 * 512 / 8);

    // 4. attn = hh @ Wo  (split-K x8: Kc=512, 1024 blocks)
    gemm_bt<OUT_F32A, false, false, true><<<dim3(4, 32, 8), blk, 0, stream>>>(
        Vb, WoT, nullptr, attn, nullptr, nullptr, 4096, 512, 4096, 0, 0, 1.f);

    // 5. y1 = LN(x + attn)  (+ bf16 copy)
    add_ln_kernel<true><<<dim3(4096), blk, 0, stream>>>(x, attn, g1, beta1, y1, y1b);

    // 6. f1 = relu(y1 @ Wf1 + bf1)  (bf16 out)
    gemm_bt<OUT_BF16, true, true, false><<<dim3(16, 32, 1), blk, 0, stream>>>(
        y1b, Wf1T, bf1, f1b, nullptr, nullptr, 4096, 2048, 512, 0, 0, 1.f);

    // 7. ff = f1 @ Wf2 + bf2  (split-K x8: Kc=256, 1024 blocks)
    gemm_bt<OUT_F32A, true, false, true><<<dim3(4, 32, 8), blk, 0, stream>>>(
        f1b, Wf2T, bf2, ff, nullptr, nullptr, 4096, 512, 2048, 0, 0, 1.f);

    // 8. out = LN(y1 + ff)
    add_ln_kernel<false><<<dim3(4096), blk, 0, stream>>>(y1, ff, g2, beta2, out, nullptr);
}

// Round 4
// 289.715 us; speedup vs baseline: 1.3046x; 1.3046x over previous
//
#include <hip/hip_runtime.h>
#include <stdint.h>

// ---------------------------------------------------------------------------
// H=512, N=8, B=4, T=1024.  All GEMMs bf16 MFMA (m97 structure):
//   128x128 tile, BK=32, 4 waves (2x2), 4x4 frags of 16x16x32 MFMA,
//   global_load_lds width-16 staging, 2-barrier K-loop.
// Attention trick: hh[b,a,t,:] = attn_diag * V, and row-scaling per head
//   commutes with @Wo:  (d∘V)@Wo = sum_a d_a * (V_a @ Wo_a).
//   -> batched per-head partials U_a (no split-K, no atomics), folded with
//   d factors into the LN1 kernel.
// Wf2 (N=512): split-K x4 into partial buffers, summed in the LN2 kernel.
// ---------------------------------------------------------------------------

#define LN_EPS 1e-5f

typedef __attribute__((ext_vector_type(8))) short short8;
typedef __attribute__((ext_vector_type(4))) float f32x4;

__device__ __forceinline__ unsigned short f2bf(float f) {
    unsigned int u = __float_as_uint(f);
    u = (u + 0x7fffu + ((u >> 16) & 1u)) >> 16;
    return (unsigned short)u;
}
__device__ __forceinline__ float bf2f(unsigned short h) {
    return __uint_as_float(((unsigned int)h) << 16);
}

__device__ __forceinline__ void llds16(const void* g, void* l) {
    __builtin_amdgcn_global_load_lds(
        (const __attribute__((address_space(1))) void*)g,
        (__attribute__((address_space(3))) void*)l, 16, 0, 0);
}

#define OUT_F32 0
#define OUT_BF16 1
#define OUT_ATTN 2

// ---------------------------------------------------------------------------
// bf16 MFMA GEMM: C = act(A @ Bt^T + bias).  M,N multiples of 128; K of 32.
// lda/ldb: element stride between rows of A / Bt (>= K for sub-slices).
// SPLITK: blockIdx.z = K-chunk (Kc=K/gridDim.z), C_z = Cv + z*cBatch.
// else  : blockIdx.z = batch; offsets aBatch/bBatch/cBatch (elements).
// ---------------------------------------------------------------------------
template <int MODE, bool BIAS, bool RELU, bool SPLITK>
__global__ __launch_bounds__(256) void gemm_bt(
    const unsigned short* __restrict__ A,
    const unsigned short* __restrict__ Bt,
    const float* __restrict__ bias,
    void* __restrict__ Cv,
    float* __restrict__ dsum,               // ATTN: [32768] f32 (pre-zeroed)
    float* __restrict__ ddiag,              // ATTN: [32768] f32
    int M, int N, int K, int lda, int ldb,
    long aBatch, long bBatch, long cBatch, float scale) {
    __shared__ unsigned short As[128 * 32];  // [row][k] 64B rows
    __shared__ unsigned short Bs[128 * 32];

    const int tid = threadIdx.x;
    const int wid = tid >> 6;
    const int lane = tid & 63;
    const int lr = lane & 15;   // fragment row/col within 16
    const int kg = lane >> 4;   // k-group 0..3
    const int wr = wid >> 1;
    const int wc = wid & 1;
    const int row0 = blockIdx.y * 128;
    const int col0 = blockIdx.x * 128;

    const unsigned short* Ab = A;
    const unsigned short* Bb = Bt;
    long cOff = 0;
    int kbeg = 0, kend = K;
    if (SPLITK) {
        const int Kc = K / gridDim.z;
        kbeg = blockIdx.z * Kc;
        kend = kbeg + Kc;
        cOff = (long)blockIdx.z * cBatch;
    } else {
        Ab += (long)blockIdx.z * aBatch;
        Bb += (long)blockIdx.z * bBatch;
        cOff = (long)blockIdx.z * cBatch;
    }

    // staging: per wave 2 calls of 1KB each for A and B
    const int rS = wid * 32 + (lane >> 2);  // row in 128-tile (call 0)
    const int k8 = (lane & 3) * 8;          // bf16 offset within 32-k row
    unsigned short* ldsA0 = &As[(wid * 2 + 0) * 512];
    unsigned short* ldsA1 = &As[(wid * 2 + 1) * 512];
    unsigned short* ldsB0 = &Bs[(wid * 2 + 0) * 512];
    unsigned short* ldsB1 = &Bs[(wid * 2 + 1) * 512];
    const unsigned short* gA0 = Ab + (long)(row0 + rS) * lda + k8;
    const unsigned short* gA1 = gA0 + (long)16 * lda;
    const unsigned short* gB0 = Bb + (long)(col0 + rS) * ldb + k8;
    const unsigned short* gB1 = gB0 + (long)16 * ldb;

    f32x4 acc[4][4];
#pragma unroll
    for (int m = 0; m < 4; ++m)
#pragma unroll
        for (int n = 0; n < 4; ++n)
#pragma unroll
            for (int j = 0; j < 4; ++j) acc[m][n][j] = 0.f;

    for (int kk = kbeg; kk < kend; kk += 32) {
        __syncthreads();  // previous ds_reads done before overwrite
        llds16(gA0 + kk, ldsA0);
        llds16(gA1 + kk, ldsA1);
        llds16(gB0 + kk, ldsB0);
        llds16(gB1 + kk, ldsB1);
        __syncthreads();  // drains vmcnt -> LDS tiles ready
        short8 a[4], b[4];
#pragma unroll
        for (int m = 0; m < 4; ++m)
            a[m] = *(const short8*)&As[(wr * 64 + m * 16 + lr) * 32 + kg * 8];
#pragma unroll
        for (int n = 0; n < 4; ++n)
            b[n] = *(const short8*)&Bs[(wc * 64 + n * 16 + lr) * 32 + kg * 8];
#pragma unroll
        for (int m = 0; m < 4; ++m)
#pragma unroll
            for (int n = 0; n < 4; ++n)
                acc[m][n] = __builtin_amdgcn_mfma_f32_16x16x32_bf16(
                    a[m], b[n], acc[m][n], 0, 0, 0);
    }

    if (MODE == OUT_ATTN) {
        // rows of this wave: row0 + wr*64 + m*16 + kg*4 + j  (per head bz)
        const int hrow0 = blockIdx.z * 1024 + row0 + wr * 64;
        const bool diagblk = (blockIdx.x == blockIdx.y) && (wr == wc);
#pragma unroll
        for (int m = 0; m < 4; ++m) {
            float es[4] = {0.f, 0.f, 0.f, 0.f};
#pragma unroll
            for (int n = 0; n < 4; ++n) {
#pragma unroll
                for (int j = 0; j < 4; ++j) {
                    float e = __expf(acc[m][n][j] * scale);
                    es[j] += e;
                    if (diagblk && n == m && lr == kg * 4 + j)
                        ddiag[hrow0 + m * 16 + kg * 4 + j] = e;
                }
            }
#pragma unroll
            for (int j = 0; j < 4; ++j) {
                float s = es[j];
                s += __shfl_xor(s, 1, 64);
                s += __shfl_xor(s, 2, 64);
                s += __shfl_xor(s, 4, 64);
                s += __shfl_xor(s, 8, 64);
                if (lr == 0) atomicAdd(&dsum[hrow0 + m * 16 + kg * 4 + j], s);
            }
        }
        return;
    }

#pragma unroll
    for (int m = 0; m < 4; ++m) {
        const int grow = row0 + wr * 64 + m * 16 + kg * 4;
#pragma unroll
        for (int n = 0; n < 4; ++n) {
            const int gcol = col0 + wc * 64 + n * 16 + lr;
            const float bv = BIAS ? bias[gcol] : 0.f;
#pragma unroll
            for (int j = 0; j < 4; ++j) {
                float v = acc[m][n][j] + bv;
                if (RELU) v = fmaxf(v, 0.f);
                if (MODE == OUT_F32)
                    ((float*)Cv)[cOff + (long)(grow + j) * N + gcol] = v;
                else
                    ((unsigned short*)Cv)[cOff + (long)(grow + j) * N + gcol] =
                        f2bf(v);
            }
        }
    }
}

// ---------------------------------------------------------------------------
// f32 [R][C] -> bf16 [C][R] transpose+convert (weights, once per launch)
// ---------------------------------------------------------------------------
__global__ __launch_bounds__(256) void transpose_bf16(
    const float* __restrict__ src, unsigned short* __restrict__ dst,
    int R, int C) {
    __shared__ float tile[32][33];
    const int tx = threadIdx.x & 31;
    const int ty = threadIdx.x >> 5;  // 0..7
    const int r0 = blockIdx.y * 32;
    const int c0 = blockIdx.x * 32;
#pragma unroll
    for (int k = 0; k < 4; ++k)
        tile[ty + k * 8][tx] = src[(long)(r0 + ty + k * 8) * C + c0 + tx];
    __syncthreads();
#pragma unroll
    for (int k = 0; k < 4; ++k)
        dst[(long)(c0 + ty + k * 8) * R + r0 + tx] = f2bf(tile[tx][ty + k * 8]);
}

// f32 -> bf16 flat convert, 8 elems/thread
__global__ __launch_bounds__(256) void convert_bf16(
    const float* __restrict__ src, unsigned short* __restrict__ dst, int n8) {
    const int idx = blockIdx.x * 256 + threadIdx.x;
    if (idx >= n8) return;
    float4 a = ((const float4*)src)[idx * 2];
    float4 b = ((const float4*)src)[idx * 2 + 1];
    uint4 o;
    o.x = (unsigned int)f2bf(a.x) | ((unsigned int)f2bf(a.y) << 16);
    o.y = (unsigned int)f2bf(a.z) | ((unsigned int)f2bf(a.w) << 16);
    o.z = (unsigned int)f2bf(b.x) | ((unsigned int)f2bf(b.y) << 16);
    o.w = (unsigned int)f2bf(b.z) | ((unsigned int)f2bf(b.w) << 16);
    ((uint4*)dst)[idx] = o;
}

// ---------------------------------------------------------------------------
// Wave/block LN reduce helper (rows of 512, 256 threads, 2 cols/thread).
// ---------------------------------------------------------------------------
__device__ __forceinline__ void ln_reduce(float v0, float v1, int tid,
                                          float* sred, float* sred2,
                                          float& mu, float& rs) {
    float sum = v0 + v1;
    float sq = v0 * v0 + v1 * v1;
#pragma unroll
    for (int off = 32; off > 0; off >>= 1) {
        sum += __shfl_down(sum, off, 64);
        sq += __shfl_down(sq, off, 64);
    }
    const int wave = tid >> 6;
    if ((tid & 63) == 0) { sred[wave] = sum; sred2[wave] = sq; }
    __syncthreads();
    if (tid == 0) {
        float s = 0.f, q = 0.f;
#pragma unroll
        for (int w = 0; w < 4; ++w) { s += sred[w]; q += sred2[w]; }
        const float m = s * (1.f / 512.f);
        const float var = q * (1.f / 512.f) - m * m;
        sred[4] = m;
        sred2[4] = rsqrtf(var + LN_EPS);
    }
    __syncthreads();
    mu = sred[4];
    rs = sred2[4];
}

// ---------------------------------------------------------------------------
// LN1: y1 = LN(x + sum_a d_a * U_a) * g + be;  y1b = bf16(y1).
// U: 8 buffers of [4096][512] f32, stride 4096*512.  d_a = ddiag/dsum at
// index (b*8+a)*1024+t, b=row>>10, t=row&1023.
// ---------------------------------------------------------------------------
__global__ __launch_bounds__(256) void ln_combine1(
    const float* __restrict__ x, const float* __restrict__ U,
    const float* __restrict__ dsum, const float* __restrict__ ddiag,
    const float* __restrict__ g, const float* __restrict__ be,
    float* __restrict__ y1, unsigned short* __restrict__ y1b) {
    __shared__ float sred[8], sred2[8], df[8];
    const int row = blockIdx.x;
    const int tid = threadIdx.x;
    if (tid < 8) {
        const int b = row >> 10, t = row & 1023;
        const int idx = (b * 8 + tid) * 1024 + t;
        df[tid] = ddiag[idx] / dsum[idx];
    }
    __syncthreads();
    const long base = (long)row * 512;
    float v0 = x[base + tid];
    float v1 = x[base + tid + 256];
#pragma unroll
    for (int a = 0; a < 8; ++a) {
        const float d = df[a];
        const long ub = (long)a * 2097152 + base;
        v0 = fmaf(d, U[ub + tid], v0);
        v1 = fmaf(d, U[ub + tid + 256], v1);
    }
    float mu, rs;
    ln_reduce(v0, v1, tid, sred, sred2, mu, rs);
    const float o0 = (v0 - mu) * rs * g[tid] + be[tid];
    const float o1 = (v1 - mu) * rs * g[tid + 256] + be[tid + 256];
    y1[base + tid] = o0;
    y1[base + tid + 256] = o1;
    y1b[base + tid] = f2bf(o0);
    y1b[base + tid + 256] = f2bf(o1);
}

// ---------------------------------------------------------------------------
// LN2: out = LN(y1 + sum_z ffp_z + bf2) * g + be.
// ffp: 4 buffers of [4096][512] f32, stride 4096*512.
// ---------------------------------------------------------------------------
__global__ __launch_bounds__(256) void ln_combine2(
    const float* __restrict__ y1, const float* __restrict__ ffp,
    const float* __restrict__ bias, const float* __restrict__ g,
    const float* __restrict__ be, float* __restrict__ out) {
    __shared__ float sred[8], sred2[8];
    const int row = blockIdx.x;
    const int tid = threadIdx.x;
    const long base = (long)row * 512;
    float v0 = y1[base + tid] + bias[tid];
    float v1 = y1[base + tid + 256] + bias[tid + 256];
#pragma unroll
    for (int z = 0; z < 4; ++z) {
        const long fb = (long)z * 2097152 + base;
        v0 += ffp[fb + tid];
        v1 += ffp[fb + tid + 256];
    }
    float mu, rs;
    ln_reduce(v0, v1, tid, sred, sred2, mu, rs);
    out[base + tid] = (v0 - mu) * rs * g[tid] + be[tid];
    out[base + tid + 256] = (v1 - mu) * rs * g[tid + 256] + be[tid + 256];
}

// ---------------------------------------------------------------------------
// Launcher
// ---------------------------------------------------------------------------
extern "C" void kernel_launch(void* const* d_in, const int* in_sizes, int n_in,
                              void* d_out, int out_size, void* d_ws, size_t ws_size,
                              hipStream_t stream) {
    const float* x     = (const float*)d_in[0];
    const float* Wq    = (const float*)d_in[1];
    const float* Wk    = (const float*)d_in[2];
    const float* Wv    = (const float*)d_in[3];
    const float* Wo    = (const float*)d_in[4];
    const float* g1    = (const float*)d_in[5];
    const float* beta1 = (const float*)d_in[6];
    const float* Wf1   = (const float*)d_in[7];
    const float* bf1   = (const float*)d_in[8];
    const float* Wf2   = (const float*)d_in[9];
    const float* bf2   = (const float*)d_in[10];
    const float* g2    = (const float*)d_in[11];
    const float* beta2 = (const float*)d_in[12];
    float* out = (float*)d_out;

    char* p = (char*)d_ws;
    unsigned short* xb   = (unsigned short*)p; p += (long)4096 * 512 * 2;
    unsigned short* WqT  = (unsigned short*)p; p += (long)4096 * 512 * 2;  // WqT/WkT/WvT contiguous
    unsigned short* WkT  = (unsigned short*)p; p += (long)4096 * 512 * 2;
    unsigned short* WvT  = (unsigned short*)p; p += (long)4096 * 512 * 2;
    unsigned short* WoT  = (unsigned short*)p; p += (long)512 * 4096 * 2;
    unsigned short* Wf1T = (unsigned short*)p; p += (long)2048 * 512 * 2;
    unsigned short* Wf2T = (unsigned short*)p; p += (long)512 * 2048 * 2;
    unsigned short* Qb   = (unsigned short*)p; p += (long)4096 * 4096 * 2;  // Qb/Kb/Vb contiguous
    unsigned short* Kb   = (unsigned short*)p; p += (long)4096 * 4096 * 2;
    unsigned short* Vb   = (unsigned short*)p; p += (long)4096 * 4096 * 2;
    float* dsum  = (float*)p; p += (long)32768 * 4;
    float* ddiag = (float*)p; p += (long)32768 * 4;
    float* U     = (float*)p; p += (long)8 * 4096 * 512 * 4;   // 8 head partials
    float* y1    = (float*)p; p += (long)4096 * 512 * 4;
    unsigned short* y1b = (unsigned short*)p; p += (long)4096 * 512 * 2;
    unsigned short* f1b = (unsigned short*)p; p += (long)4096 * 2048 * 2;
    float* ffp   = (float*)p; p += (long)4 * 4096 * 512 * 4;   // 4 K-chunk partials

    const dim3 blk(256);
    const float invs = 0.04419417382415922f;  // 1/sqrt(512)

    // 0. converts / weight transposes (bf16, B^T form)
    convert_bf16<<<dim3(1024), blk, 0, stream>>>(x, xb, 4096 * 512 / 8);
    transpose_bf16<<<dim3(4096 / 32, 512 / 32), blk, 0, stream>>>(Wq, WqT, 512, 4096);
    transpose_bf16<<<dim3(4096 / 32, 512 / 32), blk, 0, stream>>>(Wk, WkT, 512, 4096);
    transpose_bf16<<<dim3(4096 / 32, 512 / 32), blk, 0, stream>>>(Wv, WvT, 512, 4096);
    transpose_bf16<<<dim3(512 / 32, 4096 / 32), blk, 0, stream>>>(Wo, WoT, 4096, 512);
    transpose_bf16<<<dim3(2048 / 32, 512 / 32), blk, 0, stream>>>(Wf1, Wf1T, 512, 2048);
    transpose_bf16<<<dim3(512 / 32, 2048 / 32), blk, 0, stream>>>(Wf2, Wf2T, 2048, 512);
    hipMemsetAsync(dsum, 0, 32768 * sizeof(float), stream);

    // 1. QKV projections, one batched dispatch (z = q/k/v)
    gemm_bt<OUT_BF16, false, false, false><<<dim3(32, 32, 3), blk, 0, stream>>>(
        xb, WqT, nullptr, Qb, nullptr, nullptr, 4096, 4096, 512, 512, 512,
        0, (long)4096 * 512, (long)4096 * 4096, 1.f);

    // 2. logits + softmax row-sums/diag (Q,K viewed [32 heads][1024][512])
    gemm_bt<OUT_ATTN, false, false, false><<<dim3(8, 8, 32), blk, 0, stream>>>(
        Qb, Kb, nullptr, nullptr, dsum, ddiag, 1024, 1024, 512, 512, 512,
        (long)1024 * 512, (long)1024 * 512, 0, invs);

    // 3. U_a = V[:, a-slice] @ Wo[a-slice, :], batched over heads a=0..7
    gemm_bt<OUT_F32, false, false, false><<<dim3(4, 32, 8), blk, 0, stream>>>(
        Vb, WoT, nullptr, U, nullptr, nullptr, 4096, 512, 512, 4096, 4096,
        512, 512, (long)4096 * 512, 1.f);

    // 4. y1 = LN(x + sum_a d_a U_a)  (+ bf16 copy)
    ln_combine1<<<dim3(4096), blk, 0, stream>>>(x, U, dsum, ddiag, g1, beta1,
                                                y1, y1b);

    // 5. f1 = relu(y1 @ Wf1 + bf1)  (bf16 out)
    gemm_bt<OUT_BF16, true, true, false><<<dim3(16, 32, 1), blk, 0, stream>>>(
        y1b, Wf1T, bf1, f1b, nullptr, nullptr, 4096, 2048, 512, 512, 512,
        0, 0, 0, 1.f);

    // 6. ffp_z = f1 @ Wf2 (K-chunk partials, z=0..3; bias folded into LN2)
    gemm_bt<OUT_F32, false, false, true><<<dim3(4, 32, 4), blk, 0, stream>>>(
        f1b, Wf2T, nullptr, ffp, nullptr, nullptr, 4096, 512, 2048, 2048, 2048,
        0, 0, (long)4096 * 512, 1.f);

    // 7. out = LN(y1 + sum_z ffp_z + bf2)
    ln_combine2<<<dim3(4096), blk, 0, stream>>>(y1, ffp, bf2, g2, beta2, out);
}